// Round 13
// baseline (214.783 us; speedup 1.0000x reference)
//
#include <hip/hip_runtime.h>

// Batched 8x8 iDCT: out = M^T * img * M + 128
//   M[i][j] = 0.5 * a[i] * cos((2j+1)*i*pi/16)
//   a[i]    = alpha[i*8+1]       (alpha = outer(a,a), a[1]==1)
//   cos term = dct[i*512 + j*8]  (dct_tensor[i,0,j,0]; cos(0)==1)
//
// Design M: column-decomposed stage 2 -> 8x less LDS read volume.
//   - stage 1 (as R9): thread (b8,r) computes P row r of block b8 in registers
//     from its coalesced dwordx4 loads, writes 2x ds_write_b128
//   - stage 2 NEW: thread reads only P COLUMN r (8x ds_read_b32, 32B = exactly
//     the data it needs; bank = (4*b8 + r + c) mod 32 -> 2 lanes/bank = free)
//     and computes output column: O[u] = 128 + sum_x M[x][u] * P[x][r].
//     Old design: 16x broadcast ds_read_b128/thread/set = 8x redundancy,
//     ~92us of LDS-pipe time per CU (~45% occupancy) serializing vs HBM.
//   - stores: 8x b32 per block-column; each instruction writes 8 contiguous
//     32B chunks and the wave's 8 u-instructions fully cover every 64B line
//     within a few issue slots -> L2 merges, no write amplification expected
//   - barrier-free intra-wave exchange (proven R8+): wave-local lgkmcnt(0)
//   - M in SGPRs via readlane; no more per-lane mu[] loads (M covers stage 2)
//   - lb(256,4), SETS=4, one-shot WGs, plain stores (NT null per R12)

#define WG      256
#define SETS    4
#define BLKWAVE 32                    // blocks per wave (SETS * 8)
#define BLKWG   128                   // blocks per WG (4 waves)
#define STRIDE4 17                    // float4 stride per block slot in LDS

template<bool FULL>
__device__ __forceinline__ void process_tile(
    const float4* __restrict__ in4, float* __restrict__ outp,
    float4* __restrict__ lds4, const float* __restrict__ alpha,
    const float* __restrict__ dct, long long wgbase, int nblocks,
    int w, int b8, int r, int lane)
{
    const long long myblk0 = wgbase + w * BLKWAVE + b8;   // + s*8 per set

    // ---- issue ALL loads first (8 dwordx4 in flight per lane) ----
    float4 lo[SETS], hi[SETS];
#pragma unroll
    for (int s = 0; s < SETS; ++s) {
        const long long g = myblk0 + s * 8;
        if (FULL || g < nblocks) {
            const size_t p = (size_t)g * 16 + r * 2;
            lo[s] = in4[p];
            hi[s] = in4[p + 1];
        } else {
            lo[s] = make_float4(0.f, 0.f, 0.f, 0.f);
            hi[s] = lo[s];
        }
    }

    // ---- M -> SGPRs via readlane (overlaps the load latency) ----
    float mv;
    {
        const int i = lane >> 3, j = lane & 7;
        mv = 0.5f * alpha[i * 8 + 1] * dct[i * 512 + j * 8];
    }
    float M[64];
#pragma unroll
    for (int k = 0; k < 64; ++k)
        M[k] = __int_as_float(__builtin_amdgcn_readlane(__float_as_int(mv), k));

    // ---- stage 1 per set: P[v] = sum_y row[y]*M[y][v] -> LDS slot ----
#pragma unroll
    for (int s = 0; s < SETS; ++s) {
        const float row[8] = {lo[s].x, lo[s].y, lo[s].z, lo[s].w,
                              hi[s].x, hi[s].y, hi[s].z, hi[s].w};
        float P[8];
#pragma unroll
        for (int v = 0; v < 8; ++v) {
            float acc = 0.0f;
#pragma unroll
            for (int y = 0; y < 8; ++y)
                acc = fmaf(row[y], M[y * 8 + v], acc);
            P[v] = acc;
        }
        float4* buf = &lds4[(w * BLKWAVE + s * 8 + b8) * STRIDE4];
        buf[r * 2 + 0] = make_float4(P[0], P[1], P[2], P[3]);
        buf[r * 2 + 1] = make_float4(P[4], P[5], P[6], P[7]);
    }

    // wave-local: my wave's ds_writes commit in order; exchange is intra-wave
    asm volatile("s_waitcnt lgkmcnt(0)" ::: "memory");

    // ---- stage 2 per set: read P column r (8x b32), compute output column,
    //      store 8x b32 (each inst: 8 contiguous 32B chunks; lines merge) ----
#pragma unroll
    for (int s = 0; s < SETS; ++s) {
        const float* bufF = (const float*)&lds4[(w * BLKWAVE + s * 8 + b8) * STRIDE4];
        float Pc[8];
#pragma unroll
        for (int x = 0; x < 8; ++x)
            Pc[x] = bufF[x * 8 + r];          // bank: 2 lanes/bank -> free

        float O[8] = {128.f, 128.f, 128.f, 128.f, 128.f, 128.f, 128.f, 128.f};
#pragma unroll
        for (int x = 0; x < 8; ++x) {
            const float p = Pc[x];
#pragma unroll
            for (int u = 0; u < 8; ++u)
                O[u] = fmaf(M[x * 8 + u], p, O[u]);
        }

        const long long g = myblk0 + s * 8;
        if (FULL || g < nblocks) {
            float* ob = outp + ((size_t)g * 64 + r);
#pragma unroll
            for (int u = 0; u < 8; ++u)
                ob[u * 8] = O[u];
        }
    }
}

__global__ __launch_bounds__(WG, 4) void dct8x8_kernel(
    const float* __restrict__ image,
    const float* __restrict__ alpha,
    const float* __restrict__ dct,
    float* __restrict__ out,
    int nblocks)
{
    __shared__ float4 lds4[BLKWG * STRIDE4];   // 128*17*16B = 34816B

    const int t = threadIdx.x;
    const int w = t >> 6;          // wave 0..3
    const int lane = t & 63;
    const int b8 = lane >> 3;      // block-within-wave-set 0..7
    const int r = lane & 7;        // my row (stage 1) / my column (stage 2)

    const long long wgbase = (long long)blockIdx.x * BLKWG;
    const float4* in4 = (const float4*)image;

    if (wgbase + BLKWG <= (long long)nblocks) {
        process_tile<true >(in4, out, lds4, alpha, dct, wgbase, nblocks, w, b8, r, lane);
    } else {
        process_tile<false>(in4, out, lds4, alpha, dct, wgbase, nblocks, w, b8, r, lane);
    }
}

extern "C" void kernel_launch(void* const* d_in, const int* in_sizes, int n_in,
                              void* d_out, int out_size, void* d_ws, size_t ws_size,
                              hipStream_t stream) {
    const float* image = (const float*)d_in[0];
    const float* alpha = (const float*)d_in[1];
    const float* dct   = (const float*)d_in[2];
    float* outp = (float*)d_out;

    const int nblocks = in_sizes[0] / 64;
    const long long wgs = ((long long)nblocks + BLKWG - 1) / BLKWG;

    dct8x8_kernel<<<(int)wgs, WG, 0, stream>>>(image, alpha, dct, outp, nblocks);
}

// Round 14
// 211.879 us; speedup vs baseline: 1.0137x; 1.0137x over previous
//
#include <hip/hip_runtime.h>

// Batched 8x8 iDCT: out = M^T * img * M + 128
//   M[i][j] = 0.5 * a[i] * cos((2j+1)*i*pi/16)
//   a[i]    = alpha[i*8+1]       (alpha = outer(a,a), a[1]==1)
//   cos term = dct[i*512 + j*8]  (dct_tensor[i,0,j,0]; cos(0)==1)
//
// Design N: single-wave workgroups for phase decorrelation.
//   - WG = 64 = one wave; SETS=2 -> LDS 4.42KB/WG -> 32 WGs/CU resident
//     (full wave capacity), each wave launches/retires independently ->
//     load phases of the CU's 32 waves are staggered, read-issue duty
//     cycle stays high (the R9 256-thread one-shot design marches 16
//     waves in lockstep: load burst -> dead window -> compute -> store)
//   - row-per-lane (proven): lane owns one row of each of its 2 blocks,
//     all global ops dwordx4, lanes stride 32B -> fully coalesced
//   - P-exchange intra-wave (proven R8+): no barrier, wave-local
//     s_waitcnt lgkmcnt(0) only
//   - LDS stride 17 float4/block: conflict-free writes, broadcast reads
//   - M in SGPRs via readlane; plain stores (NT null R12); no prefetch
//     (null R10); one-shot WGs
//   - N_BLOCKS % 16 == 0 -> FULL guard-free path (template)

#define WG      64
#define SETS    2
#define BLKWG   16                    // blocks per WG (1 wave x 2 sets x 8)
#define STRIDE4 17                    // float4 stride per block slot in LDS

template<bool FULL>
__device__ __forceinline__ void process_tile(
    const float4* __restrict__ in4, float4* __restrict__ o4,
    float4* __restrict__ lds4, const float* __restrict__ alpha,
    const float* __restrict__ dct, long long wgbase, int nblocks,
    int b8, int r, int lane)
{
    const long long myblk0 = wgbase + b8;   // + s*8 per set

    // ---- issue ALL loads first (4 dwordx4 in flight per lane) ----
    float4 lo[SETS], hi[SETS];
#pragma unroll
    for (int s = 0; s < SETS; ++s) {
        const long long g = myblk0 + s * 8;
        if (FULL || g < nblocks) {
            const size_t p = (size_t)g * 16 + r * 2;
            lo[s] = in4[p];
            hi[s] = in4[p + 1];
        } else {
            lo[s] = make_float4(0.f, 0.f, 0.f, 0.f);
            hi[s] = lo[s];
        }
    }

    // ---- M -> SGPRs via readlane (overlaps the load latency) ----
    float mv;
    {
        const int i = lane >> 3, j = lane & 7;
        mv = 0.5f * alpha[i * 8 + 1] * dct[i * 512 + j * 8];
    }
    float M[64];
#pragma unroll
    for (int k = 0; k < 64; ++k)
        M[k] = __int_as_float(__builtin_amdgcn_readlane(__float_as_int(mv), k));

    // stage-2 weights M[x][r] (runtime r): per-lane loads, cache-hot
    float mu[8];
#pragma unroll
    for (int x = 0; x < 8; ++x)
        mu[x] = 0.5f * alpha[x * 8 + 1] * dct[x * 512 + r * 8];

    // ---- stage 1 per set: P[v] = sum_y row[y]*M[y][v] -> LDS slot ----
#pragma unroll
    for (int s = 0; s < SETS; ++s) {
        const float row[8] = {lo[s].x, lo[s].y, lo[s].z, lo[s].w,
                              hi[s].x, hi[s].y, hi[s].z, hi[s].w};
        float P[8];
#pragma unroll
        for (int v = 0; v < 8; ++v) {
            float acc = 0.0f;
#pragma unroll
            for (int y = 0; y < 8; ++y)
                acc = fmaf(row[y], M[y * 8 + v], acc);
            P[v] = acc;
        }
        float4* buf = &lds4[(s * 8 + b8) * STRIDE4];
        buf[r * 2 + 0] = make_float4(P[0], P[1], P[2], P[3]);
        buf[r * 2 + 1] = make_float4(P[4], P[5], P[6], P[7]);
    }

    // wave-local: my wave's ds_writes commit in order; exchange is intra-wave
    asm volatile("s_waitcnt lgkmcnt(0)" ::: "memory");

    // ---- stage 2 per set: O[v] = 128 + sum_x mu[x]*P[x][v]; store row ----
#pragma unroll
    for (int s = 0; s < SETS; ++s) {
        const float4* buf = &lds4[(s * 8 + b8) * STRIDE4];
        float O[8] = {128.f, 128.f, 128.f, 128.f, 128.f, 128.f, 128.f, 128.f};
#pragma unroll
        for (int x = 0; x < 8; ++x) {
            const float4 plo = buf[x * 2 + 0];
            const float4 phi = buf[x * 2 + 1];
            const float m = mu[x];
            O[0] = fmaf(m, plo.x, O[0]);
            O[1] = fmaf(m, plo.y, O[1]);
            O[2] = fmaf(m, plo.z, O[2]);
            O[3] = fmaf(m, plo.w, O[3]);
            O[4] = fmaf(m, phi.x, O[4]);
            O[5] = fmaf(m, phi.y, O[5]);
            O[6] = fmaf(m, phi.z, O[6]);
            O[7] = fmaf(m, phi.w, O[7]);
        }
        const long long g = myblk0 + s * 8;
        if (FULL || g < nblocks) {
            const size_t p = (size_t)g * 16 + r * 2;
            o4[p]     = make_float4(O[0], O[1], O[2], O[3]);
            o4[p + 1] = make_float4(O[4], O[5], O[6], O[7]);
        }
    }
}

__global__ __launch_bounds__(WG, 8) void dct8x8_kernel(
    const float* __restrict__ image,
    const float* __restrict__ alpha,
    const float* __restrict__ dct,
    float* __restrict__ out,
    int nblocks)
{
    __shared__ float4 lds4[BLKWG * STRIDE4];   // 16*17*16B = 4352B

    const int lane = threadIdx.x & 63;
    const int b8 = lane >> 3;      // block-within-set 0..7
    const int r = lane & 7;        // my row

    const long long wgbase = (long long)blockIdx.x * BLKWG;
    const float4* in4 = (const float4*)image;
    float4* o4 = (float4*)out;

    if (wgbase + BLKWG <= (long long)nblocks) {
        process_tile<true >(in4, o4, lds4, alpha, dct, wgbase, nblocks, b8, r, lane);
    } else {
        process_tile<false>(in4, o4, lds4, alpha, dct, wgbase, nblocks, b8, r, lane);
    }
}

extern "C" void kernel_launch(void* const* d_in, const int* in_sizes, int n_in,
                              void* d_out, int out_size, void* d_ws, size_t ws_size,
                              hipStream_t stream) {
    const float* image = (const float*)d_in[0];
    const float* alpha = (const float*)d_in[1];
    const float* dct   = (const float*)d_in[2];
    float* outp = (float*)d_out;

    const int nblocks = in_sizes[0] / 64;
    const long long wgs = ((long long)nblocks + BLKWG - 1) / BLKWG;

    dct8x8_kernel<<<(int)wgs, WG, 0, stream>>>(image, alpha, dct, outp, nblocks);
}

// Round 15
// 201.057 us; speedup vs baseline: 1.0683x; 1.0538x over previous
//
#include <hip/hip_runtime.h>

// Batched 8x8 iDCT: out = M^T * img * M + 128
//   M[i][j] = 0.5 * a[i] * cos((2j+1)*i*pi/16)
//   a[i]    = alpha[i*8+1]       (alpha = outer(a,a), a[1]==1)
//   cos term = dct[i*512 + j*8]  (dct_tensor[i,0,j,0]; cos(0)==1)
//
// Design O: R9 + SETS=8 (16KB read burst per wave, coarser r/w interleave).
//   - row-per-lane: lane owns one row of each of its 8 blocks; all 16
//     dwordx4 loads issued up front (256B/lane in flight), then compute
//     proceeds in two 4-set batches reusing the same LDS slots
//   - slot reuse safety: batch-B ds_writes are issued after batch-A ds_reads
//     in program order; per-wave DS ops execute in order (R8+ proven), plus
//     a compiler memory fence between batches
//   - barrier-free intra-wave P-exchange, wave-local s_waitcnt lgkmcnt(0)
//   - LDS stride 17 float4/block (34.8KB/WG, unchanged from R9)
//   - M in SGPRs via readlane; lb(256,4) = 128 VGPRs (16 data float4 fit,
//     no spill); plain stores (NT null R12); one-shot WGs (persistence null)
//   - N_BLOCKS % 256 == 0 for the bench shape -> FULL guard-free path

#define WG      256
#define SETS    8
#define BATCH   4                     // sets exchanged per LDS occupancy
#define BLKWAVE 64                    // blocks per wave (SETS * 8)
#define BLKWG   256                   // blocks per WG (4 waves)
#define STRIDE4 17                    // float4 stride per block slot in LDS

template<bool FULL>
__device__ __forceinline__ void process_tile(
    const float4* __restrict__ in4, float4* __restrict__ o4,
    float4* __restrict__ lds4, const float* __restrict__ alpha,
    const float* __restrict__ dct, long long wgbase, int nblocks,
    int w, int b8, int r, int lane)
{
    const long long myblk0 = wgbase + w * BLKWAVE + b8;   // + s*8 per set

    // ---- issue ALL loads first (16 dwordx4 in flight per lane) ----
    float4 lo[SETS], hi[SETS];
#pragma unroll
    for (int s = 0; s < SETS; ++s) {
        const long long g = myblk0 + s * 8;
        if (FULL || g < nblocks) {
            const size_t p = (size_t)g * 16 + r * 2;
            lo[s] = in4[p];
            hi[s] = in4[p + 1];
        } else {
            lo[s] = make_float4(0.f, 0.f, 0.f, 0.f);
            hi[s] = lo[s];
        }
    }

    // ---- M -> SGPRs via readlane (overlaps the load latency) ----
    float mv;
    {
        const int i = lane >> 3, j = lane & 7;
        mv = 0.5f * alpha[i * 8 + 1] * dct[i * 512 + j * 8];
    }
    float M[64];
#pragma unroll
    for (int k = 0; k < 64; ++k)
        M[k] = __int_as_float(__builtin_amdgcn_readlane(__float_as_int(mv), k));

    // stage-2 weights M[x][r] (runtime r): per-lane loads, cache-hot
    float mu[8];
#pragma unroll
    for (int x = 0; x < 8; ++x)
        mu[x] = 0.5f * alpha[x * 8 + 1] * dct[x * 512 + r * 8];

    // ---- two batches of BATCH sets, reusing the same LDS slots ----
#pragma unroll
    for (int batch = 0; batch < SETS / BATCH; ++batch) {
        // stage 1: P[v] = sum_y row[y]*M[y][v] -> LDS slot (s % BATCH)
#pragma unroll
        for (int q = 0; q < BATCH; ++q) {
            const int s = batch * BATCH + q;
            const float row[8] = {lo[s].x, lo[s].y, lo[s].z, lo[s].w,
                                  hi[s].x, hi[s].y, hi[s].z, hi[s].w};
            float P[8];
#pragma unroll
            for (int v = 0; v < 8; ++v) {
                float acc = 0.0f;
#pragma unroll
                for (int y = 0; y < 8; ++y)
                    acc = fmaf(row[y], M[y * 8 + v], acc);
                P[v] = acc;
            }
            float4* buf = &lds4[(w * (BATCH * 8) + q * 8 + b8) * STRIDE4];
            buf[r * 2 + 0] = make_float4(P[0], P[1], P[2], P[3]);
            buf[r * 2 + 1] = make_float4(P[4], P[5], P[6], P[7]);
        }

        // wave-local: my ds_writes commit in order; exchange is intra-wave
        asm volatile("s_waitcnt lgkmcnt(0)" ::: "memory");

        // stage 2: O[v] = 128 + sum_x mu[x]*P[x][v]; store row
#pragma unroll
        for (int q = 0; q < BATCH; ++q) {
            const int s = batch * BATCH + q;
            const float4* buf = &lds4[(w * (BATCH * 8) + q * 8 + b8) * STRIDE4];
            float O[8] = {128.f, 128.f, 128.f, 128.f, 128.f, 128.f, 128.f, 128.f};
#pragma unroll
            for (int x = 0; x < 8; ++x) {
                const float4 plo = buf[x * 2 + 0];
                const float4 phi = buf[x * 2 + 1];
                const float m = mu[x];
                O[0] = fmaf(m, plo.x, O[0]);
                O[1] = fmaf(m, plo.y, O[1]);
                O[2] = fmaf(m, plo.z, O[2]);
                O[3] = fmaf(m, plo.w, O[3]);
                O[4] = fmaf(m, phi.x, O[4]);
                O[5] = fmaf(m, phi.y, O[5]);
                O[6] = fmaf(m, phi.z, O[6]);
                O[7] = fmaf(m, phi.w, O[7]);
            }
            const long long g = myblk0 + s * 8;
            if (FULL || g < nblocks) {
                const size_t p = (size_t)g * 16 + r * 2;
                o4[p]     = make_float4(O[0], O[1], O[2], O[3]);
                o4[p + 1] = make_float4(O[4], O[5], O[6], O[7]);
            }
        }

        // keep batch-B ds_writes after batch-A ds_reads (HW: per-wave DS
        // ordering; compiler: same-address aliasing + this fence)
        asm volatile("" ::: "memory");
    }
}

__global__ __launch_bounds__(WG, 4) void dct8x8_kernel(
    const float* __restrict__ image,
    const float* __restrict__ alpha,
    const float* __restrict__ dct,
    float* __restrict__ out,
    int nblocks)
{
    __shared__ float4 lds4[4 * BATCH * 8 * STRIDE4];   // 128 slots = 34816B

    const int t = threadIdx.x;
    const int w = t >> 6;          // wave 0..3
    const int lane = t & 63;
    const int b8 = lane >> 3;      // block-within-set 0..7
    const int r = lane & 7;        // my row

    const long long wgbase = (long long)blockIdx.x * BLKWG;
    const float4* in4 = (const float4*)image;
    float4* o4 = (float4*)out;

    if (wgbase + BLKWG <= (long long)nblocks) {
        process_tile<true >(in4, o4, lds4, alpha, dct, wgbase, nblocks, w, b8, r, lane);
    } else {
        process_tile<false>(in4, o4, lds4, alpha, dct, wgbase, nblocks, w, b8, r, lane);
    }
}

extern "C" void kernel_launch(void* const* d_in, const int* in_sizes, int n_in,
                              void* d_out, int out_size, void* d_ws, size_t ws_size,
                              hipStream_t stream) {
    const float* image = (const float*)d_in[0];
    const float* alpha = (const float*)d_in[1];
    const float* dct   = (const float*)d_in[2];
    float* outp = (float*)d_out;

    const int nblocks = in_sizes[0] / 64;
    const long long wgs = ((long long)nblocks + BLKWG - 1) / BLKWG;

    dct8x8_kernel<<<(int)wgs, WG, 0, stream>>>(image, alpha, dct, outp, nblocks);
}